// Round 8
// baseline (232.623 us; speedup 1.0000x reference)
//
#include <hip/hip_runtime.h>
#include <stdint.h>

#define HWP 784                // 28*28
#define NPOS 50176             // 64*784 flat positions
#define PLN ((size_t)NPOS * 64)  // plane stride bytes: [g][pos][64ch]
#define SLAB_ROWS 186          // 128 pos + 2*29 halo
#define NCHUNK 2976            // 186*16 16B chunks
#define PAD_OFF 47616          // slab offset of the 256-B pad row (186*256)

typedef int   int4v   __attribute__((ext_vector_type(4)));
typedef int   int16v  __attribute__((ext_vector_type(16)));
typedef float float4v __attribute__((ext_vector_type(4)));
using as1_cv = const __attribute__((address_space(1))) void;
using as3_v  = __attribute__((address_space(3))) void;

#define SGB __builtin_amdgcn_sched_group_barrier

// ---------------- kernel 1: x NCHW fp32 -> plane-blocked i8 (value-128) -------------
__global__ __launch_bounds__(256) void k_nhwc(const float* __restrict__ x,
                                              int8_t* __restrict__ x8) {
    __shared__ int lA[256 * 15];                 // [c][pq] pos-packed, stride 15
    __shared__ __align__(16) int lB[56 * 68];    // [pos][ch-dword 0..63], stride 68
    const int tid = threadIdx.x;
    const int P0 = blockIdx.x * 56;
    const int n = P0 / HWP;
    const int hw0 = P0 % HWP;
    const float* xb = x + (size_t)n * 256 * HWP + hw0;
#pragma unroll
    for (int k = 0; k < 14; ++k) {               // 3584 float4 chunks
        int e = tid + k * 256;
        int c = e / 14, pq = e % 14;
        float4v v = *(const float4v*)(xb + (size_t)c * HWP + pq * 4);
        int b0 = ((int)v[0] - 128) & 255;
        int b1 = ((int)v[1] - 128) & 255;
        int b2 = ((int)v[2] - 128) & 255;
        int b3 = ((int)v[3] - 128) & 255;
        lA[c * 15 + pq] = b0 | (b1 << 8) | (b2 << 16) | (b3 << 24);
    }
    __syncthreads();
#pragma unroll
    for (int k = 0; k < 4; ++k) {                // 896 4x4 byte-transpose units
        int u = tid + k * 256;
        if (u < 896) {
            int cg = u / 14, pq = u % 14;
            int d0 = lA[(cg * 4 + 0) * 15 + pq];
            int d1 = lA[(cg * 4 + 1) * 15 + pq];
            int d2 = lA[(cg * 4 + 2) * 15 + pq];
            int d3 = lA[(cg * 4 + 3) * 15 + pq];
#pragma unroll
            for (int j = 0; j < 4; ++j) {
                int sh = j * 8;
                int o = ((d0 >> sh) & 255) | (((d1 >> sh) & 255) << 8)
                      | (((d2 >> sh) & 255) << 16) | (((d3 >> sh) & 255) << 24);
                lB[(pq * 4 + j) * 68 + cg] = o;
            }
        }
    }
    __syncthreads();
#pragma unroll
    for (int k = 0; k < 4; ++k) {                // 896 16B output chunks
        int ch = tid + k * 256;
        if (ch < 896) {
            int g = ch / 224, rem = ch % 224;
            int pos = rem >> 2, c4 = rem & 3;
            int4v val = *(const int4v*)&lB[pos * 68 + g * 16 + c4 * 4];
            *(int4v*)(x8 + (size_t)g * PLN + (size_t)(P0 + pos) * 64 + c4 * 16) = val;
        }
    }
}

// ---------------- kernel 2: weights OIHW fp32 -> fragment-major int8 + per-oc sums --
__global__ __launch_bounds__(256) void k_w_prep(const float* __restrict__ wa,
                                                const float* __restrict__ wb,
                                                int8_t* __restrict__ w8a,
                                                int8_t* __restrict__ w8b,
                                                int* __restrict__ wsa,
                                                int* __restrict__ wsb) {
    __shared__ int red[256];
    const int which = blockIdx.x >> 8;
    const int oc = blockIdx.x & 255;
    const float* w = which ? wb : wa;
    int8_t* w8 = which ? w8b : w8a;
    int* wsum = which ? wsb : wsa;
    const int t = threadIdx.x;          // t = ic
    const float* src = w + (size_t)oc * 2304 + (size_t)t * 9;
    const int g = oc >> 5;
    const int l = ((t >> 4) & 1) * 32 + (oc & 31);
    const int j = t & 15;
    const int s2 = (t >> 5) & 1;
    const int kb = t >> 6;
    int acc = 0;
#pragma unroll
    for (int tap = 0; tap < 9; ++tap) {
        int wv = (int)src[tap];
        acc += wv;
        int oo = ((((tap * 4 + kb) * 2 + s2) * 8 + g) * 64 + l) * 16 + j;
        w8[oo] = (int8_t)wv;
    }
    red[t] = acc;
    __syncthreads();
    for (int st = 128; st > 0; st >>= 1) {
        if (t < st) red[t] += red[t + st];
        __syncthreads();
    }
    if (t == 0) wsum[oc] = red[0];
}

// ---------------- kernel 3: quantized 3x3 conv, 128pos x 256oc blocks ---------------
// PINNED-PIPELINE ROUND (T19): VGPR evidence (R2=72, R3's explicit prefetch=84, +12
// not +48) proved hipcc CANONICALIZES source-level cross-step prefetch away -- loads
// are sunk next to consumers, each wave serializes read-phase -> MFMA-phase, and
// identically-phased waves convoy on the shared LDS/L2 pipes => measured step time =
// SUM of pipe times (5 rounds of confirmation).  Fix: keep R7's mt=4 ratio geometry,
// add A+B cross-step register prefetch AND PIN the emission order with
// sched_group_barrier: per step {4x VMEM_READ(B,u+1)} then 8x {2x MFMA(u),
// 1x DS_READ(A,u+1)} -- reads drain UNDER the MFMA cluster.  Pipeline registers
// (~+80) need (256,1): 512-reg cap, 1 block/CU, 4 waves.  At 1 block/CU the MFMA
// cluster (586 cy/step/SIMD) covers the block's own LDS (376 cy) and VMEM (293 cy)
// -> MFMA-bound if pinning holds.  Grid 392 -> 2 sequential rounds on 136 CUs.
template<bool FUSED>
__global__ __launch_bounds__(256, 1) void k_qconv_t(const int8_t* __restrict__ in8,
        const int8_t* __restrict__ w8, const int* __restrict__ wsum,
        const float* __restrict__ s_in_p, const float* __restrict__ s_w_p,
        const float* __restrict__ s_out_p, const float* __restrict__ z_in_p,
        const float* __restrict__ z_out_p, int8_t* __restrict__ out8,
        const int8_t* __restrict__ x8, const float* __restrict__ sxp,
        const float* __restrict__ zxp, const float* __restrict__ sap,
        const float* __restrict__ zap, float* __restrict__ outf) {
    __shared__ __align__(16) int8_t slab[47872];   // 186 rows x 256 B + pad row
    const int tid = threadIdx.x;
    const int lane = tid & 63;
    const int half = lane >> 5;
    const int wv = tid >> 6;           // oc plane 0..3 (wave owns 128pos x 64oc)
    const int bid = blockIdx.x;
    const int tile = (bid & 7) * 49 + (bid >> 3);   // XCD-chunk swizzle (392 = 8*49)
    const int p0 = tile * 128;
    const int plane = wv;

    // ---- stage A-slab: 2976 16B chunks; slot (q,cs) holds global chunk cs ^ (q&15)
#pragma unroll
    for (int k = 0; k < 12; ++k) {
        int chunkid = tid + k * 256;
        if (chunkid < NCHUNK) {
            int q = chunkid >> 4;
            int cs = chunkid & 15;
            int cg = cs ^ (q & 15);
            int qg = p0 - 29 + q;
            qg = qg < 0 ? 0 : (qg > NPOS - 1 ? NPOS - 1 : qg);
            const int8_t* src = in8 + (size_t)(cg >> 2) * PLN
                                    + (size_t)qg * 64 + (cg & 3) * 16;
            __builtin_amdgcn_global_load_lds((as1_cv*)src,
                                             (as3_v*)&slab[chunkid * 16], 16, 0, 0);
        }
    }

    // pad row: z_in - 128 splat
    const int zi = (int)z_in_p[0] - 128;
    const int spl = (zi & 0xff) * 0x01010101;
    if (tid < 16) {
        int4v pv; pv[0] = spl; pv[1] = spl; pv[2] = spl; pv[3] = spl;
        *(int4v*)&slab[PAD_OFF + tid * 16] = pv;
    }

    // per-lane geometry: 4 M-tiles of 32 positions each
    int rowpos[4], ph[4], pw[4];
#pragma unroll
    for (int mt = 0; mt < 4; ++mt) {
        rowpos[mt] = mt * 32 + (lane & 31);
        int p = p0 + rowpos[mt];
        int hw = p % HWP;
        ph[mt] = hw / 28;
        pw[mt] = hw % 28;
    }

    int16v acc[4][2];
#pragma unroll
    for (int mt = 0; mt < 4; ++mt)
#pragma unroll
        for (int nt = 0; nt < 2; ++nt)
#pragma unroll
            for (int r = 0; r < 16; ++r) acc[mt][nt][r] = 0;

    // B: wave's 64-oc slice (g = plane*2 + nt)
    const int8_t* wlane = w8 + plane * 2048 + lane * 16;

    __syncthreads();       // the only barrier before the K-loop

    // ---- prologue: B(0) and A(0) into current regs
    int4v bc00 = *(const int4v*)(wlane);
    int4v bc10 = *(const int4v*)(wlane + 1024);
    int4v bc01 = *(const int4v*)(wlane + 8192);
    int4v bc11 = *(const int4v*)(wlane + 9216);
    int4v ac[4][2];
#pragma unroll
    for (int mt = 0; mt < 4; ++mt) {
        int q = rowpos[mt];                         // tap0: dh=-1,dw=-1 -> +29-29
        bool ok = ((unsigned)(ph[mt] - 1) < 28u) & ((unsigned)(pw[mt] - 1) < 28u);
        int ab = (ok ? (q << 8) : PAD_OFF) ^ ((q & 15) << 4) ^ (half << 4);
        ac[mt][0] = *(const int4v*)&slab[ab];
        ac[mt][1] = *(const int4v*)&slab[ab ^ (2 << 4)];
    }

#pragma unroll
    for (int u = 0; u < 36; ++u) {
        // ---- issue step u+1's operand fetches (pinned to drain under u's MFMAs)
        int4v an[4][2], bn00, bn10, bn01, bn11;
        if (u < 35) {
            const int un = u + 1;
            const int tapn = un >> 2, kbn = un & 3;
            const int dhn = tapn / 3 - 1;
            const int dwn = tapn % 3 - 1;
            const int8_t* wb_ = wlane + (size_t)un * 16384;
            bn00 = *(const int4v*)(wb_);
            bn10 = *(const int4v*)(wb_ + 1024);
            bn01 = *(const int4v*)(wb_ + 8192);
            bn11 = *(const int4v*)(wb_ + 9216);
#pragma unroll
            for (int mt = 0; mt < 4; ++mt) {
                int q = rowpos[mt] + dhn * 28 + dwn + 29;   // 0..185
                bool ok = ((unsigned)(ph[mt] + dhn) < 28u)
                        & ((unsigned)(pw[mt] + dwn) < 28u);
                int ab = (ok ? (q << 8) : PAD_OFF) ^ ((q & 15) << 4) ^ (half << 4);
                an[mt][0] = *(const int4v*)&slab[ab ^ ((kbn * 4 + 0) << 4)];
                an[mt][1] = *(const int4v*)&slab[ab ^ ((kbn * 4 + 2) << 4)];
            }
        }
        // ---- 16 MFMAs on step u's registers (loaded one full step ago)
#pragma unroll
        for (int mt = 0; mt < 4; ++mt) {
            acc[mt][0] = __builtin_amdgcn_mfma_i32_32x32x32_i8(ac[mt][0], bc00,
                                                               acc[mt][0], 0, 0, 0);
            acc[mt][1] = __builtin_amdgcn_mfma_i32_32x32x32_i8(ac[mt][0], bc10,
                                                               acc[mt][1], 0, 0, 0);
        }
#pragma unroll
        for (int mt = 0; mt < 4; ++mt) {
            acc[mt][0] = __builtin_amdgcn_mfma_i32_32x32x32_i8(ac[mt][1], bc01,
                                                               acc[mt][0], 0, 0, 0);
            acc[mt][1] = __builtin_amdgcn_mfma_i32_32x32x32_i8(ac[mt][1], bc11,
                                                               acc[mt][1], 0, 0, 0);
        }
        // ---- T19 pin: 4 B-loads first, then {2 MFMA, 1 ds_read} x 8
        if (u < 35) {
            SGB(0x020, 4, 0);                       // VMEM_READ x4 (B u+1)
#pragma unroll
            for (int g8 = 0; g8 < 8; ++g8) {
                SGB(0x008, 2, 0);                   // MFMA x2 (step u)
                SGB(0x100, 1, 0);                   // DS_READ x1 (A u+1)
            }
            // rotate (SSA-renamed by the unroll)
#pragma unroll
            for (int mt = 0; mt < 4; ++mt) {
                ac[mt][0] = an[mt][0]; ac[mt][1] = an[mt][1];
            }
            bc00 = bn00; bc10 = bn10; bc01 = bn01; bc11 = bn11;
        }
    }

    // ---- epilogue: requant q = clip(rint(M*acc)+z_out, 0, 255) (exact integer path)
    const float Mf = s_in_p[0] * s_w_p[0] / s_out_p[0];
    const float zof = z_out_p[0];
    const int zoffi = 128 - (int)z_in_p[0];

    if (!FUSED) {
        // coalesced store path: bytes -> LDS tile (row stride 80) -> full 64B lines
        __syncthreads();                        // all waves done with slab A-data
        int8_t* tpb = slab + wv * 10240;        // 128 pos x 64 oc bytes, stride 80
#pragma unroll
        for (int mt = 0; mt < 4; ++mt)
#pragma unroll
            for (int nt = 0; nt < 2; ++nt) {
                int oc = plane * 64 + nt * 32 + (lane & 31);
                int corr = zoffi * wsum[oc];
#pragma unroll
                for (int r = 0; r < 16; ++r) {
                    int prow = (r & 3) + 8 * (r >> 2) + 4 * half;   // 32x32 C/D layout
                    int pl = mt * 32 + prow;                        // local pos 0..127
                    float q = rintf(Mf * (float)(acc[mt][nt][r] + corr)) + zof;
                    q = fminf(fmaxf(q, 0.0f), 255.0f);
                    tpb[pl * 80 + nt * 32 + (lane & 31)] = (int8_t)((int)q - 128);
                }
            }
        // same-wave readback: each lane stores rows lane and lane+64 (64B lines)
#pragma unroll
        for (int h2 = 0; h2 < 2; ++h2) {
            const int rr = h2 * 64 + lane;
            int8_t* o8p = out8 + (size_t)plane * PLN + (size_t)(p0 + rr) * 64;
            const int8_t* rowp = tpb + rr * 80;
#pragma unroll
            for (int k = 0; k < 4; ++k)
                *(int4v*)(o8p + k * 16) = *(const int4v*)(rowp + k * 16);
        }
    } else {
        // fused residual qadd: out = clip(rint(ra*(qx-zx) + rb*(q2-z2)) + za, 0, 255)
        const float ra = sxp[0] / sap[0];
        const float rb = s_out_p[0] / sap[0];
        const float zx = zxp[0];
        const float z2 = z_out_p[0];
        const float za = zap[0];
        __syncthreads();                        // all waves done with slab A-data
        float* tp = (float*)slab + wv * 2080;   // 32 pos x 64 oc fp32, stride 65
        const int pl = lane & 31;
#pragma unroll
        for (int mt = 0; mt < 4; ++mt) {
#pragma unroll
            for (int nt = 0; nt < 2; ++nt) {
                int oc = plane * 64 + nt * 32 + (lane & 31);
                int corr = zoffi * wsum[oc];
#pragma unroll
                for (int r = 0; r < 16; ++r) {
                    int prow = (r & 3) + 8 * (r >> 2) + 4 * half;
                    float q2 = rintf(Mf * (float)(acc[mt][nt][r] + corr)) + zof;
                    q2 = fminf(fmaxf(q2, 0.0f), 255.0f);
                    tp[prow * 65 + nt * 32 + (lane & 31)] = q2;
                }
            }
            // same-wave readback (DS in-order per wave; next mt overwrite is ordered)
            const int pglob = p0 + mt * 32 + pl;
            const int n = pglob / HWP;
            const int hwo = pglob % HWP;
            const int8_t* x8p = x8 + (size_t)plane * PLN + (size_t)pglob * 64 + half * 32;
            int4v r0 = *(const int4v*)x8p;
            int4v r1 = *(const int4v*)(x8p + 16);
            int xb[8];
            xb[0] = r0[0]; xb[1] = r0[1]; xb[2] = r0[2]; xb[3] = r0[3];
            xb[4] = r1[0]; xb[5] = r1[1]; xb[6] = r1[2]; xb[7] = r1[3];
            float* obase = outf + ((size_t)(n * 256 + plane * 64 + half * 32)) * HWP + hwo;
#pragma unroll
            for (int j = 0; j < 32; ++j) {
                int bv = (xb[j >> 2] >> ((j & 3) * 8)) & 255;
                int xval = (int)(int8_t)bv + 128;
                float q2 = tp[pl * 65 + half * 32 + j];
                float y = ra * ((float)xval - zx) + rb * (q2 - z2);
                float qf = rintf(y) + za;
                qf = fminf(fmaxf(qf, 0.0f), 255.0f);
                obase[(size_t)j * HWP] = qf;
            }
        }
    }
}

extern "C" void kernel_launch(void* const* d_in, const int* in_sizes, int n_in,
                              void* d_out, int out_size, void* d_ws, size_t ws_size,
                              hipStream_t stream) {
    (void)in_sizes; (void)n_in; (void)out_size; (void)ws_size;
    const float* x    = (const float*)d_in[0];
    const float* w1   = (const float*)d_in[1];
    const float* w2   = (const float*)d_in[2];
    const float* s_x  = (const float*)d_in[3];
    const float* z_x  = (const float*)d_in[4];
    const float* s_w1 = (const float*)d_in[5];
    const float* s_c1 = (const float*)d_in[6];
    const float* z_c1 = (const float*)d_in[7];
    const float* s_w2 = (const float*)d_in[8];
    const float* s_c2 = (const float*)d_in[9];
    const float* z_c2 = (const float*)d_in[10];
    const float* s_ad = (const float*)d_in[11];
    const float* z_ad = (const float*)d_in[12];
    float* out = (float*)d_out;

    // workspace layout (~26.9 MB)
    int8_t* ws    = (int8_t*)d_ws;
    int8_t* x8    = ws;                       // 4 planes x 3,211,264 = 12,845,056
    int8_t* o1    = ws + 12845056;            // 12,845,056 (conv1 out, plane-blocked)
    int8_t* w8a   = ws + 25690112;            // 589,824
    int8_t* w8b   = ws + 26279936;            // 589,824
    int*    wsum1 = (int*)(ws + 26869760);    // 1024
    int*    wsum2 = (int*)(ws + 26870784);    // 1024

    k_nhwc<<<896, 256, 0, stream>>>(x, x8);
    k_w_prep<<<512, 256, 0, stream>>>(w1, w2, w8a, w8b, wsum1, wsum2);
    k_qconv_t<false><<<392, 256, 0, stream>>>(x8, w8a, wsum1,
        s_x, s_w1, s_c1, z_x, z_c1, o1,
        nullptr, nullptr, nullptr, nullptr, nullptr, nullptr);
    k_qconv_t<true><<<392, 256, 0, stream>>>(o1, w8b, wsum2,
        s_c1, s_w2, s_c2, z_c1, z_c2, nullptr,
        x8, s_x, z_x, s_ad, z_ad, out);
}

// Round 9
// 196.556 us; speedup vs baseline: 1.1835x; 1.1835x over previous
//
#include <hip/hip_runtime.h>
#include <stdint.h>

#define HWP 784                // 28*28
#define NPOS 50176             // 64*784 flat positions
#define PLN ((size_t)NPOS * 64)  // plane stride bytes: [g][pos][64ch]
#define SLAB_ROWS 186          // 128 pos + 2*29 halo
#define NCHUNK 2976            // 186*16 16B chunks
#define PAD_OFF 47616          // slab offset of the 256-B pad row (186*256)

typedef int   int4v   __attribute__((ext_vector_type(4)));
typedef int   int16v  __attribute__((ext_vector_type(16)));
typedef float float4v __attribute__((ext_vector_type(4)));
using as1_cv = const __attribute__((address_space(1))) void;
using as3_v  = __attribute__((address_space(3))) void;

// ---------------- kernel 1 (merged): blocks 0..895 = x NCHW fp32 -> plane-blocked i8
//                                     blocks 896..1407 = weight prep (coalesced)
// The two jobs are independent; merging removes one dispatch gap.  LDS is a manual
// union: nhwc needs lA(15360)+lB(15232)=30592 B; wprep needs lds8(2304)+red(1024).
__global__ __launch_bounds__(256) void k_prep(const float* __restrict__ x,
                                              int8_t* __restrict__ x8,
                                              const float* __restrict__ wa,
                                              const float* __restrict__ wb,
                                              int8_t* __restrict__ w8a,
                                              int8_t* __restrict__ w8b,
                                              int* __restrict__ wsa,
                                              int* __restrict__ wsb) {
    __shared__ __align__(16) int8_t smem[30592];
    const int tid = threadIdx.x;
    if (blockIdx.x < 896) {
        // ---------------- NHWC repack (unchanged logic) ----------------
        int* lA = (int*)smem;                        // [c][pq] stride 15 (15360 B)
        int* lB = (int*)(smem + 15360);              // [pos][ch-dword] stride 68
        const int P0 = blockIdx.x * 56;
        const int n = P0 / HWP;
        const int hw0 = P0 % HWP;
        const float* xb = x + (size_t)n * 256 * HWP + hw0;
#pragma unroll
        for (int k = 0; k < 14; ++k) {               // 3584 float4 chunks
            int e = tid + k * 256;
            int c = e / 14, pq = e % 14;
            float4v v = *(const float4v*)(xb + (size_t)c * HWP + pq * 4);
            int b0 = ((int)v[0] - 128) & 255;
            int b1 = ((int)v[1] - 128) & 255;
            int b2 = ((int)v[2] - 128) & 255;
            int b3 = ((int)v[3] - 128) & 255;
            lA[c * 15 + pq] = b0 | (b1 << 8) | (b2 << 16) | (b3 << 24);
        }
        __syncthreads();
#pragma unroll
        for (int k = 0; k < 4; ++k) {                // 896 4x4 byte-transpose units
            int u = tid + k * 256;
            if (u < 896) {
                int cg = u / 14, pq = u % 14;
                int d0 = lA[(cg * 4 + 0) * 15 + pq];
                int d1 = lA[(cg * 4 + 1) * 15 + pq];
                int d2 = lA[(cg * 4 + 2) * 15 + pq];
                int d3 = lA[(cg * 4 + 3) * 15 + pq];
#pragma unroll
                for (int j = 0; j < 4; ++j) {
                    int sh = j * 8;
                    int o = ((d0 >> sh) & 255) | (((d1 >> sh) & 255) << 8)
                          | (((d2 >> sh) & 255) << 16) | (((d3 >> sh) & 255) << 24);
                    lB[(pq * 4 + j) * 68 + cg] = o;
                }
            }
        }
        __syncthreads();
#pragma unroll
        for (int k = 0; k < 4; ++k) {                // 896 16B output chunks
            int ch = tid + k * 256;
            if (ch < 896) {
                int g = ch / 224, rem = ch % 224;
                int pos = rem >> 2, c4 = rem & 3;
                int4v val = *(const int4v*)&lB[pos * 68 + g * 16 + c4 * 4];
                *(int4v*)(x8 + (size_t)g * PLN + (size_t)(P0 + pos) * 64 + c4 * 16) = val;
            }
        }
    } else {
        // ---------------- weight prep, COALESCED ----------------
        // old version: per-thread stride-36B float reads + 1.18M scattered byte
        // stores.  New: contiguous 1KB reads per iter; LDS byte-image of the per-oc
        // fragment layout; 144 x 16B global stores per block.
        int8_t* lds8 = smem;                         // 2304 B per-oc byte image
        int* red = (int*)(smem + 2304);              // 256-int reduction
        const int bid2 = blockIdx.x - 896;
        const int which = bid2 >> 8;
        const int oc = bid2 & 255;
        const float* w = which ? wb : wa;
        int8_t* w8 = which ? w8b : w8a;
        int* wsum = which ? wsb : wsa;
        const float* src = w + (size_t)oc * 2304;
        const int g = oc >> 5;
        const int lbase = oc & 31;
        int acc = 0;
#pragma unroll
        for (int k = 0; k < 9; ++k) {                // 2304 floats, coalesced
            int m = k * 256 + tid;
            int v = (int)src[m];
            acc += v;
            int ic = m / 9, tap = m % 9;
            int kb = ic >> 6, s2 = (ic >> 5) & 1, hi = (ic >> 4) & 1, j = ic & 15;
            lds8[((tap * 4 + kb) * 2 + s2) * 32 + hi * 16 + j] = (int8_t)v;
        }
        red[tid] = acc;
        __syncthreads();
        // 72 chunks x 2 halves = 144 16B stores
        if (tid < 144) {
            int c = tid >> 1, hi = tid & 1;          // c = (tap*4+kb)*2+s2
            int4v val = *(const int4v*)&lds8[c * 32 + hi * 16];
            size_t oo = ((size_t)(c * 8 + g) * 64 + hi * 32 + lbase) * 16;
            *(int4v*)(w8 + oo) = val;
        }
        for (int st = 128; st > 0; st >>= 1) {
            if (tid < st) red[tid] += red[tid + st];
            __syncthreads();
        }
        if (tid == 0) wsum[oc] = red[0];
    }
}

// ---------------- kernel 3: quantized 3x3 conv, 128pos x 256oc blocks ---------------
// R7 VERBATIM (best verified: 199.3us total, conv ~45us).  mt=4 ratio geometry:
// wave owns 128pos x 64oc; 4 B-loads + 8 A-reads feed 16 MFMA (256 B-bytes/MFMA).
// depth-2 B register prefetch; (256,2), 2 blocks/CU; grid 392 with XCD swizzle.
// R8's pinned-pipeline experiment (SGB + (256,1)) CONFIRMED the sum-of-pipes law is
// TLP-driven, not compiler-driven: 1 block/CU = 70us despite kept pipeline.
template<bool FUSED>
__global__ __launch_bounds__(256, 2) void k_qconv_t(const int8_t* __restrict__ in8,
        const int8_t* __restrict__ w8, const int* __restrict__ wsum,
        const float* __restrict__ s_in_p, const float* __restrict__ s_w_p,
        const float* __restrict__ s_out_p, const float* __restrict__ z_in_p,
        const float* __restrict__ z_out_p, int8_t* __restrict__ out8,
        const int8_t* __restrict__ x8, const float* __restrict__ sxp,
        const float* __restrict__ zxp, const float* __restrict__ sap,
        const float* __restrict__ zap, float* __restrict__ outf) {
    __shared__ __align__(16) int8_t slab[47872];   // 186 rows x 256 B + pad row
    const int tid = threadIdx.x;
    const int lane = tid & 63;
    const int half = lane >> 5;
    const int wv = tid >> 6;           // oc plane 0..3 (wave owns 128pos x 64oc)
    const int bid = blockIdx.x;
    const int tile = (bid & 7) * 49 + (bid >> 3);   // XCD-chunk swizzle (392 = 8*49)
    const int p0 = tile * 128;
    const int plane = wv;

    // ---- stage A-slab: 2976 16B chunks; slot (q,cs) holds global chunk cs ^ (q&15)
#pragma unroll
    for (int k = 0; k < 12; ++k) {
        int chunkid = tid + k * 256;
        if (chunkid < NCHUNK) {
            int q = chunkid >> 4;
            int cs = chunkid & 15;
            int cg = cs ^ (q & 15);
            int qg = p0 - 29 + q;
            qg = qg < 0 ? 0 : (qg > NPOS - 1 ? NPOS - 1 : qg);
            const int8_t* src = in8 + (size_t)(cg >> 2) * PLN
                                    + (size_t)qg * 64 + (cg & 3) * 16;
            __builtin_amdgcn_global_load_lds((as1_cv*)src,
                                             (as3_v*)&slab[chunkid * 16], 16, 0, 0);
        }
    }

    // pad row: z_in - 128 splat
    const int zi = (int)z_in_p[0] - 128;
    const int spl = (zi & 0xff) * 0x01010101;
    if (tid < 16) {
        int4v pv; pv[0] = spl; pv[1] = spl; pv[2] = spl; pv[3] = spl;
        *(int4v*)&slab[PAD_OFF + tid * 16] = pv;
    }

    // per-lane geometry: 4 M-tiles of 32 positions each
    int rowpos[4], ph[4], pw[4];
#pragma unroll
    for (int mt = 0; mt < 4; ++mt) {
        rowpos[mt] = mt * 32 + (lane & 31);
        int p = p0 + rowpos[mt];
        int hw = p % HWP;
        ph[mt] = hw / 28;
        pw[mt] = hw % 28;
    }

    int16v acc[4][2];
#pragma unroll
    for (int mt = 0; mt < 4; ++mt)
#pragma unroll
        for (int nt = 0; nt < 2; ++nt)
#pragma unroll
            for (int r = 0; r < 16; ++r) acc[mt][nt][r] = 0;

    // B: wave's 64-oc slice (g = plane*2 + nt)
    const int8_t* wlane = w8 + plane * 2048 + lane * 16;

    __syncthreads();       // the only barrier before the K-loop

    // depth-2 B register pipeline (proven cost-free; removes per-step B latency)
    int4v bc00 = *(const int4v*)(wlane);
    int4v bc10 = *(const int4v*)(wlane + 1024);
    int4v bc01 = *(const int4v*)(wlane + 8192);
    int4v bc11 = *(const int4v*)(wlane + 9216);

#pragma unroll
    for (int u = 0; u < 36; ++u) {
        const int tap = u >> 2, kb = u & 3;
        const int dh = tap / 3 - 1;
        const int dw = tap % 3 - 1;
        int4v bn00, bn10, bn01, bn11;
        if (u < 35) {
            const int8_t* wb_ = wlane + (size_t)(u + 1) * 16384;
            bn00 = *(const int4v*)(wb_);
            bn10 = *(const int4v*)(wb_ + 1024);
            bn01 = *(const int4v*)(wb_ + 8192);
            bn11 = *(const int4v*)(wb_ + 9216);
        }
        int4v a[4][2];                               // [mt][s]
#pragma unroll
        for (int mt = 0; mt < 4; ++mt) {
            int q = rowpos[mt] + dh * 28 + dw + 29;  // 0..185
            bool ok = ((unsigned)(ph[mt] + dh) < 28u) & ((unsigned)(pw[mt] + dw) < 28u);
            int ab = (ok ? (q << 8) : PAD_OFF) ^ ((q & 15) << 4) ^ (half << 4);
            a[mt][0] = *(const int4v*)&slab[ab ^ ((kb * 4 + 0) << 4)];
            a[mt][1] = *(const int4v*)&slab[ab ^ ((kb * 4 + 2) << 4)];
        }
        // 16 MFMA: s=0 uses bc00/bc10, s=1 uses bc01/bc11
#pragma unroll
        for (int mt = 0; mt < 4; ++mt) {
            acc[mt][0] = __builtin_amdgcn_mfma_i32_32x32x32_i8(a[mt][0], bc00,
                                                               acc[mt][0], 0, 0, 0);
            acc[mt][1] = __builtin_amdgcn_mfma_i32_32x32x32_i8(a[mt][0], bc10,
                                                               acc[mt][1], 0, 0, 0);
        }
#pragma unroll
        for (int mt = 0; mt < 4; ++mt) {
            acc[mt][0] = __builtin_amdgcn_mfma_i32_32x32x32_i8(a[mt][1], bc01,
                                                               acc[mt][0], 0, 0, 0);
            acc[mt][1] = __builtin_amdgcn_mfma_i32_32x32x32_i8(a[mt][1], bc11,
                                                               acc[mt][1], 0, 0, 0);
        }
        bc00 = bn00; bc10 = bn10; bc01 = bn01; bc11 = bn11;
    }

    // ---- epilogue: requant q = clip(rint(M*acc)+z_out, 0, 255) (exact integer path)
    const float Mf = s_in_p[0] * s_w_p[0] / s_out_p[0];
    const float zof = z_out_p[0];
    const int zoffi = 128 - (int)z_in_p[0];

    if (!FUSED) {
        // coalesced store path: bytes -> LDS tile (row stride 80) -> full 64B lines
        __syncthreads();                        // all waves done with slab A-data
        int8_t* tpb = slab + wv * 10240;        // 128 pos x 64 oc bytes, stride 80
#pragma unroll
        for (int mt = 0; mt < 4; ++mt)
#pragma unroll
            for (int nt = 0; nt < 2; ++nt) {
                int oc = plane * 64 + nt * 32 + (lane & 31);
                int corr = zoffi * wsum[oc];
#pragma unroll
                for (int r = 0; r < 16; ++r) {
                    int prow = (r & 3) + 8 * (r >> 2) + 4 * half;   // 32x32 C/D layout
                    int pl = mt * 32 + prow;                        // local pos 0..127
                    float q = rintf(Mf * (float)(acc[mt][nt][r] + corr)) + zof;
                    q = fminf(fmaxf(q, 0.0f), 255.0f);
                    tpb[pl * 80 + nt * 32 + (lane & 31)] = (int8_t)((int)q - 128);
                }
            }
        // same-wave readback: each lane stores rows lane and lane+64 (64B lines)
#pragma unroll
        for (int h2 = 0; h2 < 2; ++h2) {
            const int rr = h2 * 64 + lane;
            int8_t* o8p = out8 + (size_t)plane * PLN + (size_t)(p0 + rr) * 64;
            const int8_t* rowp = tpb + rr * 80;
#pragma unroll
            for (int k = 0; k < 4; ++k)
                *(int4v*)(o8p + k * 16) = *(const int4v*)(rowp + k * 16);
        }
    } else {
        // fused residual qadd: out = clip(rint(ra*(qx-zx) + rb*(q2-z2)) + za, 0, 255)
        const float ra = sxp[0] / sap[0];
        const float rb = s_out_p[0] / sap[0];
        const float zx = zxp[0];
        const float z2 = z_out_p[0];
        const float za = zap[0];
        __syncthreads();                        // all waves done with slab A-data
        float* tp = (float*)slab + wv * 2080;   // 32 pos x 64 oc fp32, stride 65
        const int pl = lane & 31;
#pragma unroll
        for (int mt = 0; mt < 4; ++mt) {
#pragma unroll
            for (int nt = 0; nt < 2; ++nt) {
                int oc = plane * 64 + nt * 32 + (lane & 31);
                int corr = zoffi * wsum[oc];
#pragma unroll
                for (int r = 0; r < 16; ++r) {
                    int prow = (r & 3) + 8 * (r >> 2) + 4 * half;
                    float q2 = rintf(Mf * (float)(acc[mt][nt][r] + corr)) + zof;
                    q2 = fminf(fmaxf(q2, 0.0f), 255.0f);
                    tp[prow * 65 + nt * 32 + (lane & 31)] = q2;
                }
            }
            // same-wave readback (DS in-order per wave; next mt overwrite is ordered)
            const int pglob = p0 + mt * 32 + pl;
            const int n = pglob / HWP;
            const int hwo = pglob % HWP;
            const int8_t* x8p = x8 + (size_t)plane * PLN + (size_t)pglob * 64 + half * 32;
            int4v r0 = *(const int4v*)x8p;
            int4v r1 = *(const int4v*)(x8p + 16);
            int xb[8];
            xb[0] = r0[0]; xb[1] = r0[1]; xb[2] = r0[2]; xb[3] = r0[3];
            xb[4] = r1[0]; xb[5] = r1[1]; xb[6] = r1[2]; xb[7] = r1[3];
            float* obase = outf + ((size_t)(n * 256 + plane * 64 + half * 32)) * HWP + hwo;
#pragma unroll
            for (int j = 0; j < 32; ++j) {
                int bv = (xb[j >> 2] >> ((j & 3) * 8)) & 255;
                int xval = (int)(int8_t)bv + 128;
                float q2 = tp[pl * 65 + half * 32 + j];
                float y = ra * ((float)xval - zx) + rb * (q2 - z2);
                float qf = rintf(y) + za;
                qf = fminf(fmaxf(qf, 0.0f), 255.0f);
                obase[(size_t)j * HWP] = qf;
            }
        }
    }
}

extern "C" void kernel_launch(void* const* d_in, const int* in_sizes, int n_in,
                              void* d_out, int out_size, void* d_ws, size_t ws_size,
                              hipStream_t stream) {
    (void)in_sizes; (void)n_in; (void)out_size; (void)ws_size;
    const float* x    = (const float*)d_in[0];
    const float* w1   = (const float*)d_in[1];
    const float* w2   = (const float*)d_in[2];
    const float* s_x  = (const float*)d_in[3];
    const float* z_x  = (const float*)d_in[4];
    const float* s_w1 = (const float*)d_in[5];
    const float* s_c1 = (const float*)d_in[6];
    const float* z_c1 = (const float*)d_in[7];
    const float* s_w2 = (const float*)d_in[8];
    const float* s_c2 = (const float*)d_in[9];
    const float* z_c2 = (const float*)d_in[10];
    const float* s_ad = (const float*)d_in[11];
    const float* z_ad = (const float*)d_in[12];
    float* out = (float*)d_out;

    // workspace layout (~26.9 MB)
    int8_t* ws    = (int8_t*)d_ws;
    int8_t* x8    = ws;                       // 4 planes x 3,211,264 = 12,845,056
    int8_t* o1    = ws + 12845056;            // 12,845,056 (conv1 out, plane-blocked)
    int8_t* w8a   = ws + 25690112;            // 589,824
    int8_t* w8b   = ws + 26279936;            // 589,824
    int*    wsum1 = (int*)(ws + 26869760);    // 1024
    int*    wsum2 = (int*)(ws + 26870784);    // 1024

    k_prep<<<1408, 256, 0, stream>>>(x, x8, w1, w2, w8a, w8b, wsum1, wsum2);
    k_qconv_t<false><<<392, 256, 0, stream>>>(x8, w8a, wsum1,
        s_x, s_w1, s_c1, z_x, z_c1, o1,
        nullptr, nullptr, nullptr, nullptr, nullptr, nullptr);
    k_qconv_t<true><<<392, 256, 0, stream>>>(o1, w8b, wsum2,
        s_c1, s_w2, s_c2, z_c1, z_c2, nullptr,
        x8, s_x, z_x, s_ad, z_ad, out);
}